// Round 6
// baseline (220.633 us; speedup 1.0000x reference)
//
#include <hip/hip_runtime.h>
#include <hip/hip_bf16.h>
#include <stdint.h>

#define BROWS 4096
#define DDIM  1024
#define LSTR  80   // fp8 LDS row stride bytes: 64+16 pad; mult of 16 (b128-aligned),
                   // dword stride 20 -> frag b128 reads exactly 2/bank = free

typedef float f32x4 __attribute__((ext_vector_type(4)));
typedef long  lx2   __attribute__((ext_vector_type(2)));
#define PSCALE 64.0f
#define INV_PSCALE 0.015625f

__device__ __forceinline__ int pack4_fp8(float a, float b, float c, float d) {
    int w = __builtin_amdgcn_cvt_pk_fp8_f32(a, b, 0, false);
    w = __builtin_amdgcn_cvt_pk_fp8_f32(c, d, w, true);
    return w;
}

// ---------------------------------------------------------------------------
// Kernel 1: prep — log(q)->fp8, (64*p)->fp8 in K-PERMUTED layout
//   (col ks*32+q4*8+r -> q4*16+ks*8+r within each 64-col chunk, so GEMM frag
//   reads are single b128); e[row], kl_div[row]; zero CS/CL/EL; label bitmask.
// ---------------------------------------------------------------------------
__global__ __launch_bounds__(256) void prep_kernel(
    const float* __restrict__ q, const float* __restrict__ p,
    const float* __restrict__ L,
    int* __restrict__ lq8, int* __restrict__ p8,
    uint64_t* __restrict__ Lb,
    float* __restrict__ e, float* __restrict__ kld,
    float* __restrict__ CS, float* __restrict__ CL, float* __restrict__ EL)
{
    const int row = blockIdx.x;
    const int t   = threadIdx.x;
    const int wv  = t >> 6, ln = t & 63;

    const float4* qv4 = (const float4*)(q + (size_t)row * DDIM);
    const float4* pv4 = (const float4*)(p + (size_t)row * DDIM);
    float4 qv = qv4[t];
    float4 pv = pv4[t];

    float lq0 = __logf(qv.x), lq1 = __logf(qv.y), lq2 = __logf(qv.z), lq3 = __logf(qv.w);
    float lp0 = __logf(pv.x), lp1 = __logf(pv.y), lp2 = __logf(pv.z), lp3 = __logf(pv.w);

    float esum = pv.x * lp0 + pv.y * lp1 + pv.z * lp2 + pv.w * lp3;
    float ksum = pv.x * (lp0 - lq0) + pv.y * (lp1 - lq1)
               + pv.z * (lp2 - lq2) + pv.w * (lp3 - lq3);

    // K-permutation: 4 consecutive cols share (chunk, ks, q4), differ in r
    const int c0    = t * 4;
    const int chunk = c0 >> 6;
    const int c6    = c0 & 63;
    const int ksb   = (c6 >> 5) & 1;
    const int q4v   = (c6 >> 3) & 3;
    const int rr    = c6 & 7;                       // 0 or 4
    const int newc  = chunk * 64 + q4v * 16 + ksb * 8 + rr;
    const int idx   = (row * DDIM + newc) >> 2;
    lq8[idx] = pack4_fp8(lq0, lq1, lq2, lq3);
    p8 [idx] = pack4_fp8(pv.x * PSCALE, pv.y * PSCALE, pv.z * PSCALE, pv.w * PSCALE);

    const float* Lrow = L + (size_t)row * BROWS;
    #pragma unroll
    for (int c = 0; c < 16; c++) {
        float v = Lrow[c * 256 + t];
        unsigned long long m = __ballot(v != 0.0f);
        if (ln == 0) Lb[(size_t)row * 64 + c * 4 + wv] = m;
    }

    if (t == 0) { CS[row] = 0.f; CL[row] = 0.f; EL[row] = 0.f; }

    #pragma unroll
    for (int off = 32; off > 0; off >>= 1) {
        esum += __shfl_down(esum, off);
        ksum += __shfl_down(ksum, off);
    }
    __shared__ float se[4], sk[4];
    if (ln == 0) { se[wv] = esum; sk[wv] = ksum; }
    __syncthreads();
    if (t == 0) {
        e[row]   = se[0] + se[1] + se[2] + se[3];
        kld[row] = (sk[0] + sk[1] + sk[2] + sk[3]) * (1.0f / DDIM);
    }
}

// ---------------------------------------------------------------------------
// Kernel 2: cross = log_q @ p^T, fp8 e4m3. Tile 256x128, 512 threads (8 waves
//   of 64x64), 2 blocks/CU (R4's proven barrier-overlap structure), K-chunk 64,
//   2-deep register prefetch, K-permuted b128 frag reads (conflict-free).
// ---------------------------------------------------------------------------
__global__ __launch_bounds__(512, 4) void gemm_epi_kernel(
    const uint8_t* __restrict__ A8,   // fp8 log_q [B,D] K-permuted
    const uint8_t* __restrict__ B8,   // fp8 64*p  [B,D] K-permuted
    const uint64_t* __restrict__ Lb,  // [B, B/64] bitmask
    const float*  __restrict__ e,     // [B]
    float* __restrict__ CS, float* __restrict__ CL, float* __restrict__ EL)
{
    __shared__ __align__(16) uint8_t As[256 * LSTR];  // 20 KB
    __shared__ __align__(16) uint8_t Bs[128 * LSTR];  // 10 KB

    const int t    = threadIdx.x;
    const int i0   = blockIdx.y * 256;
    const int j0   = blockIdx.x * 128;
    const int wave = t >> 6;
    const int lane = t & 63;
    const int q4   = lane >> 4;
    const int ln   = lane & 15;
    const int wrow = wave & 3;    // 4 i-subtiles of 64
    const int wcol = wave >> 2;   // 2 j-subtiles of 64

    f32x4 acc[4][4];
    #pragma unroll
    for (int a = 0; a < 4; a++)
        #pragma unroll
        for (int b = 0; b < 4; b++)
            acc[a][b] = (f32x4){0.f, 0.f, 0.f, 0.f};

    // staging: A chunk 256x64B = 1024 16B units (2/thread), B 128x64B = 512 (1/thread)
    // unit u: row = u>>2, colblk = u&3
    const int uA0 = t, uA1 = t + 512, uB0 = t;
    const uint8_t* gA0 = A8 + (size_t)(i0 + (uA0 >> 2)) * DDIM + (uA0 & 3) * 16;
    const uint8_t* gA1 = A8 + (size_t)(i0 + (uA1 >> 2)) * DDIM + (uA1 & 3) * 16;
    const uint8_t* gB0 = B8 + (size_t)(j0 + (uB0 >> 2)) * DDIM + (uB0 & 3) * 16;
    const int lA0 = (uA0 >> 2) * LSTR + (uA0 & 3) * 16;
    const int lA1 = (uA1 >> 2) * LSTR + (uA1 & 3) * 16;
    const int lB0 = (uB0 >> 2) * LSTR + (uB0 & 3) * 16;

    int4 pfA0[2], pfA1[2], pfB0[2];
    pfA0[0] = *(const int4*)(gA0);      pfA1[0] = *(const int4*)(gA1);
    pfB0[0] = *(const int4*)(gB0);
    pfA0[1] = *(const int4*)(gA0 + 64); pfA1[1] = *(const int4*)(gA1 + 64);
    pfB0[1] = *(const int4*)(gB0 + 64);

    #pragma unroll 1
    for (int c = 0; c < DDIM / 64; ++c) {
        const int buf = c & 1;
        __syncthreads();                 // prior chunk's readers done
        *(int4*)(As + lA0) = pfA0[buf];
        *(int4*)(As + lA1) = pfA1[buf];
        *(int4*)(Bs + lB0) = pfB0[buf];
        __syncthreads();                 // chunk c visible

        if (c + 2 < DDIM / 64) {         // refill slot just consumed
            const int k = (c + 2) * 64;
            pfA0[buf] = *(const int4*)(gA0 + k);
            pfA1[buf] = *(const int4*)(gA1 + k);
            pfB0[buf] = *(const int4*)(gB0 + k);
        }

        // frag reads: one b128 per subtile = [ks0 8B | ks1 8B] (K-permuted)
        lx2 a2[4], b2[4];
        #pragma unroll
        for (int mi = 0; mi < 4; mi++)
            a2[mi] = *(const lx2*)(As + (wrow * 64 + mi * 16 + ln) * LSTR + q4 * 16);
        #pragma unroll
        for (int ni = 0; ni < 4; ni++)
            b2[ni] = *(const lx2*)(Bs + (wcol * 64 + ni * 16 + ln) * LSTR + q4 * 16);

        #pragma unroll
        for (int mi = 0; mi < 4; mi++)
            #pragma unroll
            for (int ni = 0; ni < 4; ni++)
                acc[mi][ni] = __builtin_amdgcn_mfma_f32_16x16x32_fp8_fp8(
                    a2[mi].x, b2[ni].x, acc[mi][ni], 0, 0, 0);
        #pragma unroll
        for (int mi = 0; mi < 4; mi++)
            #pragma unroll
            for (int ni = 0; ni < 4; ni++)
                acc[mi][ni] = __builtin_amdgcn_mfma_f32_16x16x32_fp8_fp8(
                    a2[mi].y, b2[ni].y, acc[mi][ni], 0, 0, 0);
    }

    // ---- epilogue: C/D col = lane&15 (=j), row = quad*4+reg (=i); /PSCALE ----
    const int i_base = i0 + wrow * 64;
    const int j_base = j0 + wcol * 64;

    float e_j[4];
    #pragma unroll
    for (int ni = 0; ni < 4; ni++) e_j[ni] = e[j_base + ni * 16 + ln];

    #pragma unroll
    for (int mi = 0; mi < 4; mi++) {
        #pragma unroll
        for (int r = 0; r < 4; r++) {
            const int i = i_base + mi * 16 + q4 * 4 + r;
            const uint64_t m  = Lb[(size_t)i * 64 + (j_base >> 6)];
            const uint64_t ms = m >> ln;
            float cs = 0.f, cl = 0.f, el = 0.f;
            #pragma unroll
            for (int ni = 0; ni < 4; ni++) {
                float c = acc[mi][ni][r];
                cs += c;
                if ((ms >> (ni * 16)) & 1ull) { cl += c; el += e_j[ni]; }
            }
            #pragma unroll
            for (int s = 1; s < 16; s <<= 1) {
                cs += __shfl_xor(cs, s);
                cl += __shfl_xor(cl, s);
                el += __shfl_xor(el, s);
            }
            if (ln == 0) {
                atomicAdd(&CS[i], cs * INV_PSCALE);
                atomicAdd(&CL[i], cl * INV_PSCALE);
                atomicAdd(&EL[i], el);
            }
        }
    }
}

// ---------------------------------------------------------------------------
// Kernel 3: final — Etot = sum e; result = sum_i pos/neg
// ---------------------------------------------------------------------------
__global__ __launch_bounds__(256) void final_kernel(
    const float* __restrict__ e, const float* __restrict__ kld,
    const float* __restrict__ CS, const float* __restrict__ CL,
    const float* __restrict__ EL, float* __restrict__ out)
{
    __shared__ float sred[4];
    __shared__ float sEtot;
    const int t = threadIdx.x;
    const int wv = t >> 6, ln = t & 63;

    float s = 0.f;
    for (int j = t; j < BROWS; j += 256) s += e[j];
    #pragma unroll
    for (int off = 32; off > 0; off >>= 1) s += __shfl_down(s, off);
    if (ln == 0) sred[wv] = s;
    __syncthreads();
    if (t == 0) sEtot = sred[0] + sred[1] + sred[2] + sred[3];
    __syncthreads();
    const float Etot = sEtot;
    const float invD = 1.0f / DDIM;

    float rs = 0.f;
    for (int i = t; i < BROWS; i += 256) {
        float el = EL[i], cl = CL[i], cs = CS[i];
        float pos = kld[i] + (el - cl) * invD;
        float neg = (Etot - el - cs + cl) * invD;
        rs += pos / neg;
    }
    __syncthreads();
    #pragma unroll
    for (int off = 32; off > 0; off >>= 1) rs += __shfl_down(rs, off);
    if (ln == 0) sred[wv] = rs;
    __syncthreads();
    if (t == 0) out[0] = sred[0] + sred[1] + sred[2] + sred[3];
}

// ---------------------------------------------------------------------------
extern "C" void kernel_launch(void* const* d_in, const int* in_sizes, int n_in,
                              void* d_out, int out_size, void* d_ws, size_t ws_size,
                              hipStream_t stream)
{
    const float* q = (const float*)d_in[0];
    const float* p = (const float*)d_in[1];
    const float* L = (const float*)d_in[2];
    float* out = (float*)d_out;

    char* ws = (char*)d_ws;
    int*  lq8 = (int*)ws;                                         // 4 MB
    int*  p8  = (int*)(ws + (size_t)BROWS * DDIM);                // 4 MB
    float* e  = (float*)(ws + (size_t)BROWS * DDIM * 2);          // 16 KB
    float* kld = e + BROWS;
    float* CS  = kld + BROWS;
    float* CL  = CS + BROWS;
    float* EL  = CL + BROWS;
    uint64_t* Lb = (uint64_t*)(EL + BROWS);                       // 2 MB

    prep_kernel<<<BROWS, 256, 0, stream>>>(q, p, L, lq8, p8, Lb, e, kld, CS, CL, EL);

    dim3 grid(BROWS / 128, BROWS / 256);
    gemm_epi_kernel<<<grid, 512, 0, stream>>>(
        (const uint8_t*)lq8, (const uint8_t*)p8, Lb, e, CS, CL, EL);

    final_kernel<<<1, 256, 0, stream>>>(e, kld, CS, CL, EL, out);
}

// Round 7
// 214.452 us; speedup vs baseline: 1.0288x; 1.0288x over previous
//
#include <hip/hip_runtime.h>
#include <hip/hip_bf16.h>
#include <stdint.h>

#define BROWS 4096
#define DDIM  1024
#define LSTR  136  // fp8 LDS row stride bytes: 128 + 8 pad; dword stride 34 ->
                   // same bank geometry as R4's measured-conflict-free layout

typedef float f32x4 __attribute__((ext_vector_type(4)));
typedef long  lx2   __attribute__((ext_vector_type(2)));
#define PSCALE 64.0f
#define INV_PSCALE 0.015625f

__device__ __forceinline__ int pack4_fp8(float a, float b, float c, float d) {
    int w = __builtin_amdgcn_cvt_pk_fp8_f32(a, b, 0, false);
    w = __builtin_amdgcn_cvt_pk_fp8_f32(c, d, w, true);
    return w;
}

// ---------------------------------------------------------------------------
// Kernel 1: prep — log(q)->fp8, (64*p)->fp8 in K-PERMUTED layout: within each
//   128-col chunk, col ks*32+q4*8+r -> q4*32+ks*8+r  (ks=MFMA K-step, q4=quad)
//   so GEMM frag reads are two clean b128s. Also e[row], kl_div[row],
//   zero CS/CL/EL, label bitmask.
// ---------------------------------------------------------------------------
__global__ __launch_bounds__(256) void prep_kernel(
    const float* __restrict__ q, const float* __restrict__ p,
    const float* __restrict__ L,
    int* __restrict__ lq8, int* __restrict__ p8,
    uint64_t* __restrict__ Lb,
    float* __restrict__ e, float* __restrict__ kld,
    float* __restrict__ CS, float* __restrict__ CL, float* __restrict__ EL)
{
    const int row = blockIdx.x;
    const int t   = threadIdx.x;
    const int wv  = t >> 6, ln = t & 63;

    const float4* qv4 = (const float4*)(q + (size_t)row * DDIM);
    const float4* pv4 = (const float4*)(p + (size_t)row * DDIM);
    float4 qv = qv4[t];
    float4 pv = pv4[t];

    float lq0 = __logf(qv.x), lq1 = __logf(qv.y), lq2 = __logf(qv.z), lq3 = __logf(qv.w);
    float lp0 = __logf(pv.x), lp1 = __logf(pv.y), lp2 = __logf(pv.z), lp3 = __logf(pv.w);

    float esum = pv.x * lp0 + pv.y * lp1 + pv.z * lp2 + pv.w * lp3;
    float ksum = pv.x * (lp0 - lq0) + pv.y * (lp1 - lq1)
               + pv.z * (lp2 - lq2) + pv.w * (lp3 - lq3);

    // K-permutation within 128-col chunks; 4 consecutive cols share (ks,q4)
    const int c0    = t * 4;
    const int chunk = c0 >> 7;
    const int c7    = c0 & 127;
    const int ks    = (c7 >> 5) & 3;
    const int q4v   = (c7 >> 3) & 3;
    const int rr    = c7 & 7;                    // 0 or 4
    const int newc  = chunk * 128 + q4v * 32 + ks * 8 + rr;
    const int idx   = (row * DDIM + newc) >> 2;
    lq8[idx] = pack4_fp8(lq0, lq1, lq2, lq3);
    p8 [idx] = pack4_fp8(pv.x * PSCALE, pv.y * PSCALE, pv.z * PSCALE, pv.w * PSCALE);

    const float* Lrow = L + (size_t)row * BROWS;
    #pragma unroll
    for (int c = 0; c < 16; c++) {
        float v = Lrow[c * 256 + t];
        unsigned long long m = __ballot(v != 0.0f);
        if (ln == 0) Lb[(size_t)row * 64 + c * 4 + wv] = m;
    }

    if (t == 0) { CS[row] = 0.f; CL[row] = 0.f; EL[row] = 0.f; }

    #pragma unroll
    for (int off = 32; off > 0; off >>= 1) {
        esum += __shfl_down(esum, off);
        ksum += __shfl_down(ksum, off);
    }
    __shared__ float se[4], sk[4];
    if (ln == 0) { se[wv] = esum; sk[wv] = ksum; }
    __syncthreads();
    if (t == 0) {
        e[row]   = se[0] + se[1] + se[2] + se[3];
        kld[row] = (sk[0] + sk[1] + sk[2] + sk[3]) * (1.0f / DDIM);
    }
}

// ---------------------------------------------------------------------------
// Kernel 2: cross = log_q @ p^T, fp8 e4m3. R4's proven shell: tile 256x128,
//   512 threads (8 waves of 64x64), 2 blocks/CU, 1-DEEP register prefetch
//   (stays within the 128-reg cap -> NO scratch spill), BK=128 bytes
//   (8 chunks, half R4's barriers), LDS stride 136 B (R4's conflict-free
//   bank geometry), K-permuted 2-pass b128 frag reads.
// ---------------------------------------------------------------------------
__global__ __launch_bounds__(512, 4) void gemm_epi_kernel(
    const uint8_t* __restrict__ A8,   // fp8 log_q [B,D] K-permuted
    const uint8_t* __restrict__ B8,   // fp8 64*p  [B,D] K-permuted
    const uint64_t* __restrict__ Lb,  // [B, B/64] bitmask
    const float*  __restrict__ e,     // [B]
    float* __restrict__ CS, float* __restrict__ CL, float* __restrict__ EL)
{
    __shared__ __align__(16) uint8_t As[256 * LSTR];  // 34 KB
    __shared__ __align__(16) uint8_t Bs[128 * LSTR];  // 17 KB

    const int t    = threadIdx.x;
    const int i0   = blockIdx.y * 256;
    const int j0   = blockIdx.x * 128;
    const int wave = t >> 6;
    const int lane = t & 63;
    const int q4   = lane >> 4;
    const int ln   = lane & 15;
    const int wrow = wave & 3;    // 4 i-subtiles of 64
    const int wcol = wave >> 2;   // 2 j-subtiles of 64

    f32x4 acc[4][4];
    #pragma unroll
    for (int a = 0; a < 4; a++)
        #pragma unroll
        for (int b = 0; b < 4; b++)
            acc[a][b] = (f32x4){0.f, 0.f, 0.f, 0.f};

    // staging: A chunk 256 rows x 128 B = 2048 16B units (4/thread);
    //          B chunk 128 x 128 B = 1024 units (2/thread). unit: row=u>>3, col=(u&7)*16
    const uint8_t* gA[4]; int lA[4];
    const uint8_t* gB[2]; int lB[2];
    #pragma unroll
    for (int n = 0; n < 4; n++) {
        const int u = t + n * 512;
        gA[n] = A8 + (size_t)(i0 + (u >> 3)) * DDIM + (u & 7) * 16;
        lA[n] = (u >> 3) * LSTR + (u & 7) * 16;
    }
    #pragma unroll
    for (int n = 0; n < 2; n++) {
        const int u = t + n * 512;
        gB[n] = B8 + (size_t)(j0 + (u >> 3)) * DDIM + (u & 7) * 16;
        lB[n] = (u >> 3) * LSTR + (u & 7) * 16;
    }

    int4 pfA[4], pfB[2];
    #pragma unroll
    for (int n = 0; n < 4; n++) pfA[n] = *(const int4*)(gA[n]);
    #pragma unroll
    for (int n = 0; n < 2; n++) pfB[n] = *(const int4*)(gB[n]);

    #pragma unroll 1
    for (int c = 0; c < DDIM / 128; ++c) {
        __syncthreads();                 // prior chunk's readers done
        #pragma unroll
        for (int n = 0; n < 4; n++) *(int4*)(As + lA[n]) = pfA[n];
        #pragma unroll
        for (int n = 0; n < 2; n++) *(int4*)(Bs + lB[n]) = pfB[n];
        __syncthreads();                 // chunk c visible

        if (c + 1 < DDIM / 128) {
            const int k = (c + 1) * 128;
            #pragma unroll
            for (int n = 0; n < 4; n++) pfA[n] = *(const int4*)(gA[n] + k);
            #pragma unroll
            for (int n = 0; n < 2; n++) pfB[n] = *(const int4*)(gB[n] + k);
        }

        // two passes: pass 0 = ks0,ks1 (bytes q4*32..+16), pass 1 = ks2,ks3 (+16)
        #pragma unroll
        for (int pass = 0; pass < 2; pass++) {
            lx2 aF[4], bF[4];
            #pragma unroll
            for (int mi = 0; mi < 4; mi++)
                aF[mi] = *(const lx2*)(As + (wrow * 64 + mi * 16 + ln) * LSTR
                                          + q4 * 32 + pass * 16);
            #pragma unroll
            for (int ni = 0; ni < 4; ni++)
                bF[ni] = *(const lx2*)(Bs + (wcol * 64 + ni * 16 + ln) * LSTR
                                          + q4 * 32 + pass * 16);
            #pragma unroll
            for (int mi = 0; mi < 4; mi++)
                #pragma unroll
                for (int ni = 0; ni < 4; ni++)
                    acc[mi][ni] = __builtin_amdgcn_mfma_f32_16x16x32_fp8_fp8(
                        aF[mi].x, bF[ni].x, acc[mi][ni], 0, 0, 0);
            #pragma unroll
            for (int mi = 0; mi < 4; mi++)
                #pragma unroll
                for (int ni = 0; ni < 4; ni++)
                    acc[mi][ni] = __builtin_amdgcn_mfma_f32_16x16x32_fp8_fp8(
                        aF[mi].y, bF[ni].y, acc[mi][ni], 0, 0, 0);
        }
    }

    // ---- epilogue: C/D col = lane&15 (=j), row = quad*4+reg (=i); /PSCALE ----
    const int i_base = i0 + wrow * 64;
    const int j_base = j0 + wcol * 64;

    float e_j[4];
    #pragma unroll
    for (int ni = 0; ni < 4; ni++) e_j[ni] = e[j_base + ni * 16 + ln];

    #pragma unroll
    for (int mi = 0; mi < 4; mi++) {
        #pragma unroll
        for (int r = 0; r < 4; r++) {
            const int i = i_base + mi * 16 + q4 * 4 + r;
            const uint64_t m  = Lb[(size_t)i * 64 + (j_base >> 6)];
            const uint64_t ms = m >> ln;
            float cs = 0.f, cl = 0.f, el = 0.f;
            #pragma unroll
            for (int ni = 0; ni < 4; ni++) {
                float c = acc[mi][ni][r];
                cs += c;
                if ((ms >> (ni * 16)) & 1ull) { cl += c; el += e_j[ni]; }
            }
            #pragma unroll
            for (int s = 1; s < 16; s <<= 1) {
                cs += __shfl_xor(cs, s);
                cl += __shfl_xor(cl, s);
                el += __shfl_xor(el, s);
            }
            if (ln == 0) {
                atomicAdd(&CS[i], cs * INV_PSCALE);
                atomicAdd(&CL[i], cl * INV_PSCALE);
                atomicAdd(&EL[i], el);
            }
        }
    }
}

// ---------------------------------------------------------------------------
// Kernel 3: final — Etot = sum e; result = sum_i pos/neg
// ---------------------------------------------------------------------------
__global__ __launch_bounds__(256) void final_kernel(
    const float* __restrict__ e, const float* __restrict__ kld,
    const float* __restrict__ CS, const float* __restrict__ CL,
    const float* __restrict__ EL, float* __restrict__ out)
{
    __shared__ float sred[4];
    __shared__ float sEtot;
    const int t = threadIdx.x;
    const int wv = t >> 6, ln = t & 63;

    float s = 0.f;
    for (int j = t; j < BROWS; j += 256) s += e[j];
    #pragma unroll
    for (int off = 32; off > 0; off >>= 1) s += __shfl_down(s, off);
    if (ln == 0) sred[wv] = s;
    __syncthreads();
    if (t == 0) sEtot = sred[0] + sred[1] + sred[2] + sred[3];
    __syncthreads();
    const float Etot = sEtot;
    const float invD = 1.0f / DDIM;

    float rs = 0.f;
    for (int i = t; i < BROWS; i += 256) {
        float el = EL[i], cl = CL[i], cs = CS[i];
        float pos = kld[i] + (el - cl) * invD;
        float neg = (Etot - el - cs + cl) * invD;
        rs += pos / neg;
    }
    __syncthreads();
    #pragma unroll
    for (int off = 32; off > 0; off >>= 1) rs += __shfl_down(rs, off);
    if (ln == 0) sred[wv] = rs;
    __syncthreads();
    if (t == 0) out[0] = sred[0] + sred[1] + sred[2] + sred[3];
}

// ---------------------------------------------------------------------------
extern "C" void kernel_launch(void* const* d_in, const int* in_sizes, int n_in,
                              void* d_out, int out_size, void* d_ws, size_t ws_size,
                              hipStream_t stream)
{
    const float* q = (const float*)d_in[0];
    const float* p = (const float*)d_in[1];
    const float* L = (const float*)d_in[2];
    float* out = (float*)d_out;

    char* ws = (char*)d_ws;
    int*  lq8 = (int*)ws;                                         // 4 MB
    int*  p8  = (int*)(ws + (size_t)BROWS * DDIM);                // 4 MB
    float* e  = (float*)(ws + (size_t)BROWS * DDIM * 2);          // 16 KB
    float* kld = e + BROWS;
    float* CS  = kld + BROWS;
    float* CL  = CS + BROWS;
    float* EL  = CL + BROWS;
    uint64_t* Lb = (uint64_t*)(EL + BROWS);                       // 2 MB

    prep_kernel<<<BROWS, 256, 0, stream>>>(q, p, L, lq8, p8, Lb, e, kld, CS, CL, EL);

    dim3 grid(BROWS / 128, BROWS / 256);
    gemm_epi_kernel<<<grid, 512, 0, stream>>>(
        (const uint8_t*)lq8, (const uint8_t*)p8, Lb, e, CS, CL, EL);

    final_kernel<<<1, 256, 0, stream>>>(e, kld, CS, CL, EL, out);
}